// Round 3
// baseline (27464.132 us; speedup 1.0000x reference)
//
#include <hip/hip_runtime.h>
#include <hip/hip_cooperative_groups.h>
#include <hip/hip_fp8.h>
#include <cstdint>
#include <cstddef>

namespace cg = cooperative_groups;

typedef _Float16 f16;
typedef _Float16 f16x8 __attribute__((ext_vector_type(8)));
typedef float f32x4 __attribute__((ext_vector_type(4)));

#define MFMA16(a,b,c) __builtin_amdgcn_mfma_f32_16x16x32_f16((a),(b),(c),0,0,0)
#define MFMA8(a,b,c)  __builtin_amdgcn_mfma_f32_16x16x32_fp8_fp8((a),(b),(c),0,0,0)

constexpr int Bb = 64, Tt = 48, Ee = 620, Hh = 2400;
constexpr int G3 = 3*Hh;        // 7200
constexpr int EPAD = 640;
constexpr int JT = Hh/16;       // 150
constexpr int KK_HH = Hh/32;    // 75
constexpr int KK_IH = EPAD/32;  // 20
constexpr int NT_ALL = G3/16;   // 450

// cooperative partition: 225 blocks; block b: ntg = b/3 (6 nt-tiles), ks = b%3 (25 kk)
constexpr int NBLK = 225;
constexpr int NTPB = 6;
constexpr int KKPB = 25;
constexpr int NQ   = 6;         // K-slices = 3 block-ks x 2 wave-k2

constexpr size_t WHH_ELEMS = (size_t)NT_ALL*KK_HH*64*8;  // 17,280,000 (f16)
constexpr size_t WIH_ELEMS = (size_t)NT_ALL*KK_IH*64*8;  // 4,608,000  (f16)
constexpr size_t X_ELEMS   = (size_t)Bb*Tt*EPAD;
constexpr size_t GI_ELEMS  = (size_t)Bb*Tt*G3;
constexpr size_t HB        = (size_t)Bb*Hh;              // 153,600
constexpr size_t PART_ELEMS = (size_t)NT_ALL*NQ*Bb*16;   // 2,764,800 f32

constexpr float F16_MIN_NORMAL = 6.103515625e-05f;
constexpr float LO_SCALE = 65536.0f;
constexpr float LO_INV   = 1.0f/65536.0f;

__device__ __forceinline__ float sigf(float x){ return 1.0f/(1.0f+expf(-x)); }
__device__ __forceinline__ unsigned char to_fp8(float x){
    __hip_fp8_e4m3 v(x); return *(unsigned char*)&v;
}

// ---- pack w_hh: hi = f16 frags, lo8 = fp8 e4m3 of (w-hi)*2^16, same frag order ----
__global__ __launch_bounds__(256) void k_pack_whh(const float* __restrict__ w,
                                                  f16* __restrict__ hi,
                                                  unsigned char* __restrict__ lo8){
    size_t idx = (size_t)blockIdx.x*256 + threadIdx.x;
    if (idx >= WHH_ELEMS) return;
    int j = (int)(idx & 7);
    int l = (int)((idx >> 3) & 63);
    size_t rem = idx >> 9;
    int kk = (int)(rem % KK_HH);
    int nt = (int)(rem / KK_HH);
    int row = nt*16 + (l & 15);
    int k   = kk*32 + ((l >> 4) << 3) + j;
    float v = w[(size_t)row*Hh + k];
    f16 h = (fabsf(v) >= F16_MIN_NORMAL) ? (f16)v : (f16)0.0f;
    hi[idx]  = h;
    lo8[idx] = to_fp8((v - (float)h) * LO_SCALE);
}

__global__ __launch_bounds__(256) void k_pack_wih(const float* __restrict__ w, f16* __restrict__ p){
    size_t idx = (size_t)blockIdx.x*256 + threadIdx.x;
    if (idx >= WIH_ELEMS) return;
    int j = (int)(idx & 7);
    int l = (int)((idx >> 3) & 63);
    size_t rem = idx >> 9;
    int kk = (int)(rem % KK_IH);
    int nt = (int)(rem / KK_IH);
    int row = nt*16 + (l & 15);
    int k   = kk*32 + ((l >> 4) << 3) + j;
    float v = (k < Ee) ? w[(size_t)row*Ee + k] : 0.0f;
    p[idx] = (f16)v;
}

__global__ __launch_bounds__(256) void k_gather_x(const int* __restrict__ tokens,
                                                  const float* __restrict__ emb,
                                                  f16* __restrict__ x){
    size_t idx = (size_t)blockIdx.x*256 + threadIdx.x;
    if (idx >= X_ELEMS) return;
    int row = (int)(idx / EPAD);
    int e   = (int)(idx % EPAD);
    int tok = tokens[row];
    float v = (e < Ee) ? emb[(size_t)tok*Ee + e] : 0.0f;
    x[idx] = (f16)v;
}

// ---- gi = x @ w_ih^T: 4 waves x (2 M-tiles x 3 nt), peeled prefetch ----
__global__ __launch_bounds__(256,2) void k_gi_gemm(const f16* __restrict__ x,
                                                   const f16* __restrict__ wp,
                                                   f16* __restrict__ gi){
    const int wv = threadIdx.x >> 6;
    const int l  = threadIdx.x & 63;
    const int m0  = blockIdx.x*128 + wv*32;   // 2 M-tiles: rows m0..m0+31
    const int nt0 = blockIdx.y*3;

    f32x4 z4 = {0.f,0.f,0.f,0.f};
    f32x4 acc[2][3] = {{z4,z4,z4},{z4,z4,z4}};

    const f16x8* pa0 = (const f16x8*)(x + (size_t)(m0 + (l & 15))*EPAD + ((l >> 4) << 3));
    const f16x8* pa1 = pa0 + (size_t)16*EPAD/8;
    const f16x8* pb0 = (const f16x8*)(wp + ((size_t)(nt0+0)*KK_IH*64 + l)*8);
    const f16x8* pb1 = (const f16x8*)(wp + ((size_t)(nt0+1)*KK_IH*64 + l)*8);
    const f16x8* pb2 = (const f16x8*)(wp + ((size_t)(nt0+2)*KK_IH*64 + l)*8);

    f16x8 ca0 = pa0[0], ca1 = pa1[0], cb0 = pb0[0], cb1 = pb1[0], cb2 = pb2[0];
    #pragma unroll
    for (int kk=0; kk<KK_IH-1; ++kk){
        f16x8 na0 = pa0[(size_t)(kk+1)*4];
        f16x8 na1 = pa1[(size_t)(kk+1)*4];
        f16x8 nb0 = pb0[(size_t)(kk+1)*64];
        f16x8 nb1 = pb1[(size_t)(kk+1)*64];
        f16x8 nb2 = pb2[(size_t)(kk+1)*64];
        acc[0][0] = MFMA16(ca0, cb0, acc[0][0]);
        acc[1][0] = MFMA16(ca1, cb0, acc[1][0]);
        acc[0][1] = MFMA16(ca0, cb1, acc[0][1]);
        acc[1][1] = MFMA16(ca1, cb1, acc[1][1]);
        acc[0][2] = MFMA16(ca0, cb2, acc[0][2]);
        acc[1][2] = MFMA16(ca1, cb2, acc[1][2]);
        ca0=na0; ca1=na1; cb0=nb0; cb1=nb1; cb2=nb2;
    }
    acc[0][0] = MFMA16(ca0, cb0, acc[0][0]);
    acc[1][0] = MFMA16(ca1, cb0, acc[1][0]);
    acc[0][1] = MFMA16(ca0, cb1, acc[0][1]);
    acc[1][1] = MFMA16(ca1, cb1, acc[1][1]);
    acc[0][2] = MFMA16(ca0, cb2, acc[0][2]);
    acc[1][2] = MFMA16(ca1, cb2, acc[1][2]);

    const int rb = (l >> 4)*4;
    #pragma unroll
    for (int mt=0; mt<2; ++mt){
        #pragma unroll
        for (int r=0; r<4; ++r){
            int m = m0 + mt*16 + rb + r;
            int b = m / Tt, t = m % Tt;
            size_t base = ((size_t)t*Bb + b)*G3;
            int n0 = nt0*16 + (l & 15);
            gi[base + n0     ] = (f16)acc[mt][0][r];
            gi[base + n0 + 16] = (f16)acc[mt][1][r];
            gi[base + n0 + 32] = (f16)acc[mt][2][r];
        }
    }
}

// ---- persistent cooperative recurrence ----
struct CoopArgs {
    const f16* whip;            // f16 W_hh hi frags
    const unsigned char* wlo8;  // fp8 W_hh lo frags (x2^16)
    const f16* gip;
    const float* bhh;
    const int* lens;
    float* out;
    f16* hhi[2]; f16* hlo[2]; unsigned char* h8[2]; float* h32[2];
    float* part;
};

__global__ __launch_bounds__(256,1) void k_coop(CoopArgs A){
    extern __shared__ char smem[];
    cg::grid_group grid = cg::this_grid();

    const int tid = threadIdx.x;
    const int bid = blockIdx.x;
    const int l   = tid & 63;
    const int wv  = tid >> 6;
    const int m2  = wv & 1;        // M-half (32 rows)
    const int k2  = wv >> 1;       // K-half of block's 25 kk
    const int ntg = bid / 3;       // 0..74 -> nt = ntg*6 .. +5
    const int ks  = bid % 3;       // kk base = ks*25
    const int nt0 = ntg*NTPB;
    const int q   = ks*2 + k2;     // K-slice id 0..5

    // --- load this block's W_hi slice (6 nt x 25 kk x 1KB = 150 KB) into LDS ---
    {
        const char* src = (const char*)A.whip;
        for (int c = tid; c < 9600; c += 256){
            int ntl = c / 1600;            // 1600 x16B chunks per nt (25 kk x 1KB)
            int rem = c - ntl*1600;
            size_t soff = (((size_t)(nt0+ntl)*KK_HH + ks*KKPB)*512)*2 + (size_t)rem*16;
            *(float4*)(smem + (size_t)c*16) = *(const float4*)(src + soff);
        }
        __syncthreads();
    }

    const int kb = k2 ? 13 : 0;
    const int ke = k2 ? 25 : 13;
    // A-operand row bases (2 M-tiles in this wave's M-half)
    const size_t r0 = (size_t)(m2*32 + (l & 15))*Hh;
    const size_t r1 = r0 + (size_t)16*Hh;
    const int klane = ((l >> 4) << 3);

    for (int t = 0; t < Tt; ++t){
        const int c = t & 1;
        const f16* Hhi = A.hhi[c];
        const f16* Hlo = A.hlo[c];
        const unsigned char* H8 = A.h8[c];

        f32x4 z4 = {0.f,0.f,0.f,0.f};
        f32x4 ah[2][6] = {{z4,z4,z4,z4,z4,z4},{z4,z4,z4,z4,z4,z4}};
        f32x4 al[2][6] = {{z4,z4,z4,z4,z4,z4},{z4,z4,z4,z4,z4,z4}};

        int koff = ks*800 + kb*32 + klane;
        f16x8 chi0 = *(const f16x8*)(Hhi + r0 + koff);
        f16x8 chi1 = *(const f16x8*)(Hhi + r1 + koff);
        f16x8 clo0 = *(const f16x8*)(Hlo + r0 + koff);
        f16x8 clo1 = *(const f16x8*)(Hlo + r1 + koff);
        long  cq0  = *(const long*)(H8 + r0 + koff);
        long  cq1  = *(const long*)(H8 + r1 + koff);
        long cw[6];
        #pragma unroll
        for (int n=0; n<6; ++n)
            cw[n] = *(const long*)(A.wlo8 + ((size_t)(nt0+n)*KK_HH + ks*KKPB + kb)*512 + l*8);

        for (int kk = kb; kk < ke; ++kk){
            f16x8 nhi0, nhi1, nlo0, nlo1; long nq0, nq1, nw[6];
            if (kk+1 < ke){
                int ko = ks*800 + (kk+1)*32 + klane;
                nhi0 = *(const f16x8*)(Hhi + r0 + ko);
                nhi1 = *(const f16x8*)(Hhi + r1 + ko);
                nlo0 = *(const f16x8*)(Hlo + r0 + ko);
                nlo1 = *(const f16x8*)(Hlo + r1 + ko);
                nq0  = *(const long*)(H8 + r0 + ko);
                nq1  = *(const long*)(H8 + r1 + ko);
                #pragma unroll
                for (int n=0; n<6; ++n)
                    nw[n] = *(const long*)(A.wlo8 + ((size_t)(nt0+n)*KK_HH + ks*KKPB + kk+1)*512 + l*8);
            }
            #pragma unroll
            for (int n=0; n<6; ++n){
                f16x8 wh = *(const f16x8*)(smem + ((size_t)n*KKPB + (kk - ks*KKPB*0 - 0) - 0)*0 + ((size_t)n*25 + (kk))*0 + 0 + ((size_t)n*25600 + (size_t)kk*1024 + (size_t)l*16));
                ah[0][n] = MFMA16(chi0, wh, ah[0][n]);
                ah[1][n] = MFMA16(chi1, wh, ah[1][n]);
                al[0][n] = MFMA16(clo0, wh, al[0][n]);
                al[1][n] = MFMA16(clo1, wh, al[1][n]);
                al[0][n] = MFMA8(cq0, cw[n], al[0][n]);
                al[1][n] = MFMA8(cq1, cw[n], al[1][n]);
            }
            if (kk+1 < ke){
                chi0=nhi0; chi1=nhi1; clo0=nlo0; clo1=nlo1; cq0=nq0; cq1=nq1;
                #pragma unroll
                for (int n=0; n<6; ++n) cw[n] = nw[n];
            }
        }

        // write partials: part[nt][q][b][jc]
        const int rb4 = (l >> 4)*4;
        #pragma unroll
        for (int mt=0; mt<2; ++mt){
            #pragma unroll
            for (int n=0; n<6; ++n){
                #pragma unroll
                for (int r=0; r<4; ++r){
                    int brow = m2*32 + mt*16 + rb4 + r;
                    float v = ah[mt][n][r] + al[mt][n][r]*LO_INV;
                    A.part[(((size_t)(nt0+n)*NQ + q)*Bb + brow)*16 + (l & 15)] = v;
                }
            }
        }

        grid.sync();

        // ---- combine phase (grid-stride over 153,600 h elements) ----
        const int nn = c ^ 1;
        for (int idx = bid*256 + tid; idx < (int)HB; idx += NBLK*256){
            int b = idx / Hh, j = idx - b*Hh;
            int jt = j >> 4, jc = j & 15;
            float s[3];
            #pragma unroll
            for (int g=0; g<3; ++g){
                float a = 0.f;
                #pragma unroll
                for (int qq=0; qq<NQ; ++qq)
                    a += A.part[(((size_t)(g*JT + jt)*NQ + qq)*Bb + b)*16 + jc];
                s[g] = a;
            }
            const f16* git = A.gip + ((size_t)t*Bb + b)*G3;
            float rg = sigf((float)git[j]          + s[0] + A.bhh[j]);
            float zg = sigf((float)git[Hh + j]     + s[1] + A.bhh[Hh + j]);
            float ng = tanhf((float)git[2*Hh + j]  + rg*(s[2] + A.bhh[2*Hh + j]));
            float hp = A.h32[c][idx];
            float hn = (1.0f - zg)*ng + zg*hp;
            A.h32[nn][idx] = hn;
            f16 hi16 = (fabsf(hn) >= F16_MIN_NORMAL) ? (f16)hn : (f16)0.0f;
            A.hhi[nn][idx] = hi16;
            A.hlo[nn][idx] = (f16)((hn - (float)hi16)*LO_SCALE);
            A.h8[nn][idx]  = to_fp8(hn);
            if (A.lens[b] - 1 == t) A.out[idx] = hn;
        }

        grid.sync();
    }
}

// ---- fallback (small ws or failed cooperative launch): plain fp32 ----
__global__ __launch_bounds__(256) void k_fb_step(
    int t, const float* __restrict__ hcur, float* __restrict__ hnext,
    const int* __restrict__ tokens, const int* __restrict__ lens,
    const float* __restrict__ emb, const float* __restrict__ wih,
    const float* __restrict__ whh, const float* __restrict__ bhh,
    float* __restrict__ out)
{
    __shared__ float sbuf[64][17];
    __shared__ int stok[64];
    const int tid = threadIdx.x;
    const int jl = tid & 7, rl = tid >> 3;
    const int j = blockIdx.x*8 + jl;
    if (tid < 64) stok[tid] = tokens[tid*Tt + t];

    float accr[2]={0.f,0.f}, accz[2]={0.f,0.f}, accnh[2]={0.f,0.f}, accni[2]={0.f,0.f};

    for (int k0=0; k0<Hh; k0+=16){
        __syncthreads();
        for (int e=tid; e<1024; e+=256)
            sbuf[e>>4][e&15] = hcur[(size_t)(e>>4)*Hh + k0 + (e&15)];
        __syncthreads();
        for (int kk=0; kk<16; ++kk){
            int k = k0 + kk;
            float wr = whh[(size_t)j*Hh + k];
            float wz = whh[(size_t)(Hh + j)*Hh + k];
            float wn = whh[(size_t)(2*Hh + j)*Hh + k];
            #pragma unroll
            for (int rr=0; rr<2; ++rr){
                float hv = sbuf[rl*2 + rr][kk];
                accr[rr] += wr*hv; accz[rr] += wz*hv; accnh[rr] += wn*hv;
            }
        }
    }
    for (int k0=0; k0<Ee; k0+=16){
        int lim = (Ee - k0 < 16) ? (Ee - k0) : 16;
        __syncthreads();
        for (int e=tid; e<1024; e+=256){
            int rr = e>>4, kkk = e&15;
            sbuf[rr][kkk] = (kkk < lim) ? emb[(size_t)stok[rr]*Ee + k0 + kkk] : 0.0f;
        }
        __syncthreads();
        for (int kk=0; kk<lim; ++kk){
            int k = k0 + kk;
            float wr = wih[(size_t)j*Ee + k];
            float wz = wih[(size_t)(Hh + j)*Ee + k];
            float wn = wih[(size_t)(2*Hh + j)*Ee + k];
            #pragma unroll
            for (int rr=0; rr<2; ++rr){
                float hv = sbuf[rl*2 + rr][kk];
                accr[rr] += wr*hv; accz[rr] += wz*hv; accni[rr] += wn*hv;
            }
        }
    }
    const float br = bhh[j], bz = bhh[Hh + j], bn = bhh[2*Hh + j];
    #pragma unroll
    for (int rr=0; rr<2; ++rr){
        int b = rl*2 + rr;
        float rg = sigf(accr[rr] + br);
        float zg = sigf(accz[rr] + bz);
        float ng = tanhf(accni[rr] + rg*(accnh[rr] + bn));
        float hp = hcur[(size_t)b*Hh + j];
        float hn = (1.0f - zg)*ng + zg*hp;
        hnext[(size_t)b*Hh + j] = hn;
        if (lens[b] - 1 == t) out[(size_t)b*Hh + j] = hn;
    }
}

static inline size_t alignup(size_t x){ return (x + 255) & ~(size_t)255; }

extern "C" void kernel_launch(void* const* d_in, const int* in_sizes, int n_in,
                              void* d_out, int out_size, void* d_ws, size_t ws_size,
                              hipStream_t stream)
{
    const int*   tokens = (const int*)d_in[0];
    const int*   lens   = (const int*)d_in[1];
    const float* emb    = (const float*)d_in[2];
    const float* wih    = (const float*)d_in[3];
    const float* whh    = (const float*)d_in[4];
    const float* bhh    = (const float*)d_in[5];
    float* out = (float*)d_out;

    char* ws = (char*)d_ws;
    size_t o = 0;
    const size_t o_whi  = o; o = alignup(o + WHH_ELEMS*2);
    const size_t o_wlo8 = o; o = alignup(o + WHH_ELEMS);
    const size_t o_wih  = o; o = alignup(o + WIH_ELEMS*2);
    const size_t o_x    = o; o = alignup(o + X_ELEMS*2);
    const size_t o_gi   = o; o = alignup(o + GI_ELEMS*2);
    const size_t o_part = o; o = alignup(o + PART_ELEMS*4);
    const size_t o_hbuf = o; o = alignup(o + 2*(HB*2 + HB*2 + HB + HB*4));
    const size_t need = o;   // ~115 MB

    bool coop_ok = false;
    if (ws_size >= need) {
        CoopArgs A;
        A.whip = (const f16*)(ws + o_whi);
        A.wlo8 = (const unsigned char*)(ws + o_wlo8);
        A.gip  = (const f16*)(ws + o_gi);
        A.bhh  = bhh; A.lens = lens; A.out = out;
        A.part = (float*)(ws + o_part);
        char* hb = ws + o_hbuf;
        size_t hbytes = HB*2 + HB*2 + HB + HB*4;   // hi, lo, h8, h32 per buffer
        for (int i=0; i<2; ++i){
            char* p = hb + i*hbytes;
            A.hhi[i] = (f16*)p;
            A.hlo[i] = (f16*)(p + HB*2);
            A.h8[i]  = (unsigned char*)(p + HB*4);
            A.h32[i] = (float*)(p + HB*5);
        }
        f16* wihp = (f16*)(ws + o_wih);
        f16* xp   = (f16*)(ws + o_x);

        hipMemsetAsync(hb, 0, 2*hbytes, stream);
        k_pack_whh<<<dim3((unsigned)((WHH_ELEMS+255)/256)), dim3(256), 0, stream>>>(
            whh, (f16*)(ws + o_whi), (unsigned char*)(ws + o_wlo8));
        k_pack_wih<<<dim3((unsigned)((WIH_ELEMS+255)/256)), dim3(256), 0, stream>>>(wih, wihp);
        k_gather_x<<<dim3((unsigned)((X_ELEMS+255)/256)),  dim3(256), 0, stream>>>(tokens, emb, xp);
        k_gi_gemm<<<dim3(24,150), dim3(256), 0, stream>>>(xp, wihp, (f16*)(ws + o_gi));

        hipFuncSetAttribute((const void*)k_coop,
                            hipFuncAttributeMaxDynamicSharedMemorySize, 156672);
        void* args[] = { &A };
        hipError_t e = hipLaunchCooperativeKernel((const void*)k_coop,
                            dim3(NBLK), dim3(256), args, 153600, stream);
        coop_ok = (e == hipSuccess);
    }

    if (!coop_ok) {
        // fp32 fallback (also used if cooperative launch unsupported)
        float* h32 = (float*)ws;
        float* hbuf[2] = { h32, h32 + HB };
        hipMemsetAsync(ws, 0, 2*HB*4, stream);
        for (int t=0; t<Tt; ++t){
            int c = t & 1, n = c ^ 1;
            k_fb_step<<<dim3(300), dim3(256), 0, stream>>>(t, hbuf[c], hbuf[n],
                tokens, lens, emb, wih, whh, bhh, out);
        }
    }
}

// Round 4
// 2774.621 us; speedup vs baseline: 9.8983x; 9.8983x over previous
//
#include <hip/hip_runtime.h>
#include <hip/hip_fp8.h>
#include <cstdint>
#include <cstddef>

typedef _Float16 f16;
typedef _Float16 f16x8 __attribute__((ext_vector_type(8)));
typedef float f32x4 __attribute__((ext_vector_type(4)));

#define MFMA16(a,b,c) __builtin_amdgcn_mfma_f32_16x16x32_f16((a),(b),(c),0,0,0)
#define MFMA8(a,b,c)  __builtin_amdgcn_mfma_f32_16x16x32_fp8_fp8((a),(b),(c),0,0,0)

constexpr int Bb = 64, Tt = 48, Ee = 620, Hh = 2400;
constexpr int G3 = 3*Hh;        // 7200
constexpr int EPAD = 640;
constexpr int JT = Hh/16;       // 150
constexpr int KK_HH = Hh/32;    // 75
constexpr int KK_IH = EPAD/32;  // 20
constexpr int NT_ALL = G3/16;   // 450

// persistent partition: 75 j-groups (32 j) x 3 K-slices (800) = 225 blocks
constexpr int NG = 75;          // j-groups
constexpr int NS = 3;           // K-slices per group
constexpr int KSL = 800;        // K per slice
constexpr int KKS = 25;         // kk per slice
constexpr int GRID_RNN = 240;   // 8-XCD-aligned slot grid (15 dead)

constexpr size_t WHH_ELEMS = (size_t)NT_ALL*KK_HH*64*8;  // 17,280,000
constexpr size_t WIH_ELEMS = (size_t)NT_ALL*KK_IH*64*8;  // 4,608,000
constexpr size_t X_ELEMS   = (size_t)Bb*Tt*EPAD;
constexpr size_t GI_ELEMS  = (size_t)Bb*Tt*G3;
constexpr size_t HB        = (size_t)Bb*Hh;              // 153,600
constexpr size_t PART_ELEMS = (size_t)NG*6*6*4*256;      // 2,764,800 f32

constexpr float F16_MIN_NORMAL = 6.103515625e-05f;
constexpr float LO_SCALE = 8388608.0f;   // 2^23
constexpr float LO_INV   = 1.0f/8388608.0f;

__device__ __forceinline__ float sigf(float x){ return 1.0f/(1.0f+expf(-x)); }
__device__ __forceinline__ unsigned char to_fp8(float x){
    __hip_fp8_e4m3 v(x); return *(unsigned char*)&v;
}

// ---- pack w_hh: hi f16 frags + lo fp8 (residual x 2^23), frag layout:
// elem (nt,kk,l,j): W[nt*16+(l&15)][kk*32+((l>>4)<<3)+j]
__global__ __launch_bounds__(256) void k_pack_whh(const float* __restrict__ w,
                                                  f16* __restrict__ hi,
                                                  unsigned char* __restrict__ lo8){
    size_t idx = (size_t)blockIdx.x*256 + threadIdx.x;
    if (idx >= WHH_ELEMS) return;
    int j = (int)(idx & 7);
    int l = (int)((idx >> 3) & 63);
    size_t rem = idx >> 9;
    int kk = (int)(rem % KK_HH);
    int nt = (int)(rem / KK_HH);
    int row = nt*16 + (l & 15);
    int k   = kk*32 + ((l >> 4) << 3) + j;
    float v = w[(size_t)row*Hh + k];
    f16 h = (fabsf(v) >= F16_MIN_NORMAL) ? (f16)v : (f16)0.0f;
    hi[idx]  = h;
    lo8[idx] = to_fp8((v - (float)h) * LO_SCALE);
}

__global__ __launch_bounds__(256) void k_pack_wih(const float* __restrict__ w, f16* __restrict__ p){
    size_t idx = (size_t)blockIdx.x*256 + threadIdx.x;
    if (idx >= WIH_ELEMS) return;
    int j = (int)(idx & 7);
    int l = (int)((idx >> 3) & 63);
    size_t rem = idx >> 9;
    int kk = (int)(rem % KK_IH);
    int nt = (int)(rem / KK_IH);
    int row = nt*16 + (l & 15);
    int k   = kk*32 + ((l >> 4) << 3) + j;
    float v = (k < Ee) ? w[(size_t)row*Ee + k] : 0.0f;
    p[idx] = (f16)v;
}

__global__ __launch_bounds__(256) void k_gather_x(const int* __restrict__ tokens,
                                                  const float* __restrict__ emb,
                                                  f16* __restrict__ x){
    size_t idx = (size_t)blockIdx.x*256 + threadIdx.x;
    if (idx >= X_ELEMS) return;
    int row = (int)(idx / EPAD);
    int e   = (int)(idx % EPAD);
    int tok = tokens[row];
    float v = (e < Ee) ? emb[(size_t)tok*Ee + e] : 0.0f;
    x[idx] = (f16)v;
}

// ---- gi = x @ w_ih^T: 4 waves x (2 M-tiles x 3 nt), peeled prefetch ----
__global__ __launch_bounds__(256,2) void k_gi_gemm(const f16* __restrict__ x,
                                                   const f16* __restrict__ wp,
                                                   f16* __restrict__ gi){
    const int wv = threadIdx.x >> 6;
    const int l  = threadIdx.x & 63;
    const int m0  = blockIdx.x*128 + wv*32;
    const int nt0 = blockIdx.y*3;

    f32x4 z4 = {0.f,0.f,0.f,0.f};
    f32x4 acc[2][3] = {{z4,z4,z4},{z4,z4,z4}};

    const f16x8* pa0 = (const f16x8*)(x + (size_t)(m0 + (l & 15))*EPAD + ((l >> 4) << 3));
    const f16x8* pa1 = pa0 + (size_t)16*EPAD/8;
    const f16x8* pb0 = (const f16x8*)(wp + ((size_t)(nt0+0)*KK_IH*64 + l)*8);
    const f16x8* pb1 = (const f16x8*)(wp + ((size_t)(nt0+1)*KK_IH*64 + l)*8);
    const f16x8* pb2 = (const f16x8*)(wp + ((size_t)(nt0+2)*KK_IH*64 + l)*8);

    f16x8 ca0 = pa0[0], ca1 = pa1[0], cb0 = pb0[0], cb1 = pb1[0], cb2 = pb2[0];
    #pragma unroll
    for (int kk=0; kk<KK_IH-1; ++kk){
        f16x8 na0 = pa0[(size_t)(kk+1)*4];
        f16x8 na1 = pa1[(size_t)(kk+1)*4];
        f16x8 nb0 = pb0[(size_t)(kk+1)*64];
        f16x8 nb1 = pb1[(size_t)(kk+1)*64];
        f16x8 nb2 = pb2[(size_t)(kk+1)*64];
        acc[0][0] = MFMA16(ca0, cb0, acc[0][0]);
        acc[1][0] = MFMA16(ca1, cb0, acc[1][0]);
        acc[0][1] = MFMA16(ca0, cb1, acc[0][1]);
        acc[1][1] = MFMA16(ca1, cb1, acc[1][1]);
        acc[0][2] = MFMA16(ca0, cb2, acc[0][2]);
        acc[1][2] = MFMA16(ca1, cb2, acc[1][2]);
        ca0=na0; ca1=na1; cb0=nb0; cb1=nb1; cb2=nb2;
    }
    acc[0][0] = MFMA16(ca0, cb0, acc[0][0]);
    acc[1][0] = MFMA16(ca1, cb0, acc[1][0]);
    acc[0][1] = MFMA16(ca0, cb1, acc[0][1]);
    acc[1][1] = MFMA16(ca1, cb1, acc[1][1]);
    acc[0][2] = MFMA16(ca0, cb2, acc[0][2]);
    acc[1][2] = MFMA16(ca1, cb2, acc[1][2]);

    const int rb = (l >> 4)*4;
    #pragma unroll
    for (int mt=0; mt<2; ++mt){
        #pragma unroll
        for (int r=0; r<4; ++r){
            int m = m0 + mt*16 + rb + r;
            int b = m / Tt, t = m % Tt;
            size_t base = ((size_t)t*Bb + b)*G3;
            int n0 = nt0*16 + (l & 15);
            gi[base + n0     ] = (f16)acc[mt][0][r];
            gi[base + n0 + 16] = (f16)acc[mt][1][r];
            gi[base + n0 + 32] = (f16)acc[mt][2][r];
        }
    }
}

// ---- persistent recurrence: W_hi LDS-resident, custom XCD-local sync ----
struct RnnArgs {
    const f16* whip;
    const unsigned char* wlo8;
    const f16* gip;
    const float* bhh;
    const int* lens;
    float* out;
    f16* hhi[2]; f16* hlo[2]; unsigned char* h8[2]; float* h32[2];
    float* part;
    int* sync;    // [0..74] cnt1, [75..149] cnt2, [150..224] done-flags
};

__global__ __launch_bounds__(512,2) void k_rnn(RnnArgs A){
    extern __shared__ char smem[];
    // bid -> (group g, slice s), co-locating a group's 3 slices on one XCD (bid%8)
    const int x = blockIdx.x & 7, kslot = blockIdx.x >> 3;
    const int gx = kslot/3, s = kslot - gx*3;
    const int g = gx*8 + x;
    if (g >= NG) return;

    const int tid = threadIdx.x;
    const int l = tid & 63, wv = tid >> 6;
    const int m = wv & 3, kh = wv >> 2;

    // --- stage W_hi slice (6 nt x 25 kk x 1KB = 153.6 KB) into LDS ---
    {
        const char* src = (const char*)A.whip;
        for (int c = tid; c < 9600; c += 512){
            int nti = c / 1600;
            int rem = c - nti*1600;
            int kk  = rem >> 6;
            int b16 = rem & 63;
            int ntg = (nti>>1)*JT + 2*g + (nti&1);
            size_t srcoff = ((size_t)ntg*KK_HH + s*KKS + kk)*1024 + (size_t)b16*16;
            *(float4*)(smem + (size_t)c*16) = *(const float4*)(src + srcoff);
        }
        __syncthreads();
    }

    const int kb = kh ? 13 : 0, kcnt = kh ? 12 : 13;
    const int row = m*16 + (l & 15);
    const int kl8 = (l >> 4) << 3;
    const int sl = s*2 + kh;

    unsigned ldsbase[6];
    const uint64_t* wb64[6];
    #pragma unroll
    for (int n=0; n<6; ++n){
        ldsbase[n] = n*25600u + l*16u;
        int ntg = (n>>1)*JT + 2*g + (n&1);
        wb64[n] = (const uint64_t*)(A.wlo8 + ((size_t)ntg*KK_HH + s*KKS)*512 + l*8);
    }
    int* sy = A.sync;

    for (int t = 0; t < Tt; ++t){
        const int cur = t & 1, nxt = cur ^ 1;
        {
            const f16* Hhi = A.hhi[cur];
            const f16* Hlo = A.hlo[cur];
            const unsigned char* H8 = A.h8[cur];
            const size_t abase = (size_t)row*Hh + s*KSL + kl8;
            const f16x8* pah = (const f16x8*)(Hhi + abase);
            const f16x8* pal = (const f16x8*)(Hlo + abase);
            const uint64_t* pq = (const uint64_t*)(H8 + abase);

            f32x4 z4 = {0.f,0.f,0.f,0.f};
            f32x4 acch[6] = {z4,z4,z4,z4,z4,z4};
            f32x4 accl[6] = {z4,z4,z4,z4,z4,z4};

            f16x8 cah = pah[(size_t)kb*4], cal = pal[(size_t)kb*4];
            uint64_t cq = pq[(size_t)kb*4];
            f16x8 cbh[6]; uint64_t cw[6];
            #pragma unroll
            for (int n=0; n<6; ++n){
                cbh[n] = *(const f16x8*)(smem + ldsbase[n] + (unsigned)kb*1024u);
                cw[n]  = wb64[n][(size_t)kb*64];
            }
            for (int it=0; it<kcnt-1; ++it){
                const int kn = kb + it + 1;
                f16x8 nah = pah[(size_t)kn*4], nal = pal[(size_t)kn*4];
                uint64_t nq = pq[(size_t)kn*4];
                f16x8 nbh[6]; uint64_t nw[6];
                #pragma unroll
                for (int n=0; n<6; ++n){
                    nbh[n] = *(const f16x8*)(smem + ldsbase[n] + (unsigned)kn*1024u);
                    nw[n]  = wb64[n][(size_t)kn*64];
                }
                #pragma unroll
                for (int n=0; n<6; ++n){
                    acch[n] = MFMA16(cah, cbh[n], acch[n]);
                    accl[n] = MFMA16(cal, cbh[n], accl[n]);
                    accl[n] = MFMA8((long)cq, (long)cw[n], accl[n]);
                }
                cah = nah; cal = nal; cq = nq;
                #pragma unroll
                for (int n=0; n<6; ++n){ cbh[n] = nbh[n]; cw[n] = nw[n]; }
            }
            #pragma unroll
            for (int n=0; n<6; ++n){
                acch[n] = MFMA16(cah, cbh[n], acch[n]);
                accl[n] = MFMA16(cal, cbh[n], accl[n]);
                accl[n] = MFMA8((long)cq, (long)cw[n], accl[n]);
            }
            // partial store (coalesced f32x4/lane), combined hi+lo
            #pragma unroll
            for (int n=0; n<6; ++n){
                f32x4 v = acch[n] + accl[n]*LO_INV;
                int base = ((g*6 + sl)*6 + n)*4 + m;
                ((f32x4*)(A.part + (size_t)base*256))[l] = v;
            }
        }
        // ---- group barrier (3 blocks, same XCD) ----
        __syncthreads();
        if (tid == 0){
            __hip_atomic_fetch_add(&sy[g], 1, __ATOMIC_ACQ_REL, __HIP_MEMORY_SCOPE_AGENT);
            while (__hip_atomic_load(&sy[g], __ATOMIC_ACQUIRE, __HIP_MEMORY_SCOPE_AGENT) < 3*(t+1))
                __builtin_amdgcn_s_sleep(2);
        }
        __syncthreads();
        // ---- combine: this block handles its b-range for the group's 32 j ----
        {
            const int boff = (s==0) ? 0 : (s==1) ? 22 : 43;
            const int bcnt = (s==0) ? 22 : 21;
            for (int i = tid; i < bcnt*32; i += 512){
                const int b = boff + (i >> 5), jj = i & 31;
                const int jg = g*32 + jj;
                float sums[3];
                #pragma unroll
                for (int gate=0; gate<3; ++gate){
                    const int nti = gate*2 + (jj>>4);
                    const int lane = (jj & 15) + ((b>>2)&3)*16;
                    float a = 0.f;
                    #pragma unroll
                    for (int sl2=0; sl2<6; ++sl2)
                        a += A.part[((size_t)((g*6+sl2)*6 + nti)*4 + (b>>4))*256 + lane*4 + (b&3)];
                    sums[gate] = a;
                }
                const f16* git = A.gip + ((size_t)t*Bb + b)*G3;
                float rg = sigf((float)git[jg]        + sums[0] + A.bhh[jg]);
                float zg = sigf((float)git[Hh + jg]   + sums[1] + A.bhh[Hh + jg]);
                float ng = tanhf((float)git[2*Hh + jg] + rg*(sums[2] + A.bhh[2*Hh + jg]));
                const size_t hidx = (size_t)b*Hh + jg;
                float hp = A.h32[cur][hidx];
                float hn = (1.0f - zg)*ng + zg*hp;
                A.h32[nxt][hidx] = hn;
                f16 h16 = (fabsf(hn) >= F16_MIN_NORMAL) ? (f16)hn : (f16)0.0f;
                A.hhi[nxt][hidx] = h16;
                A.hlo[nxt][hidx] = (f16)((hn - (float)h16)*LO_SCALE);
                A.h8[nxt][hidx]  = to_fp8(hn);
                if (A.lens[b] - 1 == t) A.out[hidx] = hn;
            }
        }
        if (t == Tt-1) break;
        // ---- global barrier: group-done flags, 75-way poll ----
        __syncthreads();
        if (tid == 0){
            int old = __hip_atomic_fetch_add(&sy[NG + g], 1, __ATOMIC_ACQ_REL, __HIP_MEMORY_SCOPE_AGENT);
            if (old == 3*t + 2)
                __hip_atomic_store(&sy[2*NG + g], t+1, __ATOMIC_RELEASE, __HIP_MEMORY_SCOPE_AGENT);
        }
        if (tid < NG){
            while (__hip_atomic_load(&sy[2*NG + tid], __ATOMIC_ACQUIRE, __HIP_MEMORY_SCOPE_AGENT) < t+1)
                __builtin_amdgcn_s_sleep(4);
        }
        __syncthreads();
    }
}

// ---- fallback (small ws / no coop): plain fp32 ----
__global__ __launch_bounds__(256) void k_fb_step(
    int t, const float* __restrict__ hcur, float* __restrict__ hnext,
    const int* __restrict__ tokens, const int* __restrict__ lens,
    const float* __restrict__ emb, const float* __restrict__ wih,
    const float* __restrict__ whh, const float* __restrict__ bhh,
    float* __restrict__ out)
{
    __shared__ float sbuf[64][17];
    __shared__ int stok[64];
    const int tid = threadIdx.x;
    const int jl = tid & 7, rl = tid >> 3;
    const int j = blockIdx.x*8 + jl;
    if (tid < 64) stok[tid] = tokens[tid*Tt + t];

    float accr[2]={0.f,0.f}, accz[2]={0.f,0.f}, accnh[2]={0.f,0.f}, accni[2]={0.f,0.f};

    for (int k0=0; k0<Hh; k0+=16){
        __syncthreads();
        for (int e=tid; e<1024; e+=256)
            sbuf[e>>4][e&15] = hcur[(size_t)(e>>4)*Hh + k0 + (e&15)];
        __syncthreads();
        for (int kk=0; kk<16; ++kk){
            int k = k0 + kk;
            float wr = whh[(size_t)j*Hh + k];
            float wz = whh[(size_t)(Hh + j)*Hh + k];
            float wn = whh[(size_t)(2*Hh + j)*Hh + k];
            #pragma unroll
            for (int rr=0; rr<2; ++rr){
                float hv = sbuf[rl*2 + rr][kk];
                accr[rr] += wr*hv; accz[rr] += wz*hv; accnh[rr] += wn*hv;
            }
        }
    }
    for (int k0=0; k0<Ee; k0+=16){
        int lim = (Ee - k0 < 16) ? (Ee - k0) : 16;
        __syncthreads();
        for (int e=tid; e<1024; e+=256){
            int rr = e>>4, kkk = e&15;
            sbuf[rr][kkk] = (kkk < lim) ? emb[(size_t)stok[rr]*Ee + k0 + kkk] : 0.0f;
        }
        __syncthreads();
        for (int kk=0; kk<lim; ++kk){
            int k = k0 + kk;
            float wr = wih[(size_t)j*Ee + k];
            float wz = wih[(size_t)(Hh + j)*Ee + k];
            float wn = wih[(size_t)(2*Hh + j)*Ee + k];
            #pragma unroll
            for (int rr=0; rr<2; ++rr){
                float hv = sbuf[rl*2 + rr][kk];
                accr[rr] += wr*hv; accz[rr] += wz*hv; accni[rr] += wn*hv;
            }
        }
    }
    const float br = bhh[j], bz = bhh[Hh + j], bn = bhh[2*Hh + j];
    #pragma unroll
    for (int rr=0; rr<2; ++rr){
        int b = rl*2 + rr;
        float rg = sigf(accr[rr] + br);
        float zg = sigf(accz[rr] + bz);
        float ng = tanhf(accni[rr] + rg*(accnh[rr] + bn));
        float hp = hcur[(size_t)b*Hh + j];
        float hn = (1.0f - zg)*ng + zg*hp;
        hnext[(size_t)b*Hh + j] = hn;
        if (lens[b] - 1 == t) out[(size_t)b*Hh + j] = hn;
    }
}

static inline size_t alignup(size_t v){ return (v + 255) & ~(size_t)255; }

extern "C" void kernel_launch(void* const* d_in, const int* in_sizes, int n_in,
                              void* d_out, int out_size, void* d_ws, size_t ws_size,
                              hipStream_t stream)
{
    const int*   tokens = (const int*)d_in[0];
    const int*   lens   = (const int*)d_in[1];
    const float* emb    = (const float*)d_in[2];
    const float* wih    = (const float*)d_in[3];
    const float* whh    = (const float*)d_in[4];
    const float* bhh    = (const float*)d_in[5];
    float* out = (float*)d_out;

    char* ws = (char*)d_ws;
    size_t o = 0;
    const size_t o_whi  = o; o = alignup(o + WHH_ELEMS*2);
    const size_t o_wlo8 = o; o = alignup(o + WHH_ELEMS);
    const size_t o_wih  = o; o = alignup(o + WIH_ELEMS*2);
    const size_t o_x    = o; o = alignup(o + X_ELEMS*2);
    const size_t o_gi   = o; o = alignup(o + GI_ELEMS*2);
    const size_t o_part = o; o = alignup(o + PART_ELEMS*4);
    const size_t hbytes = HB*2 + HB*2 + HB + HB*4;       // hi, lo, h8, h32
    const size_t o_hbuf = o; o = alignup(o + 2*hbytes + 1024);  // + sync ints
    const size_t need = o;   // ~123 MB

    bool ok = false;
    if (ws_size >= need) {
        RnnArgs A;
        A.whip = (const f16*)(ws + o_whi);
        A.wlo8 = (const unsigned char*)(ws + o_wlo8);
        A.gip  = (const f16*)(ws + o_gi);
        A.bhh  = bhh; A.lens = lens; A.out = out;
        A.part = (float*)(ws + o_part);
        char* hb = ws + o_hbuf;
        for (int i=0; i<2; ++i){
            char* p = hb + i*hbytes;
            A.hhi[i] = (f16*)p;
            A.hlo[i] = (f16*)(p + HB*2);
            A.h8[i]  = (unsigned char*)(p + HB*4);
            A.h32[i] = (float*)(p + HB*5);
        }
        A.sync = (int*)(hb + 2*hbytes);
        f16* wihp = (f16*)(ws + o_wih);
        f16* xp   = (f16*)(ws + o_x);

        hipMemsetAsync(hb, 0, 2*hbytes + 1024, stream);
        k_pack_whh<<<dim3((unsigned)((WHH_ELEMS+255)/256)), dim3(256), 0, stream>>>(
            whh, (f16*)(ws + o_whi), (unsigned char*)(ws + o_wlo8));
        k_pack_wih<<<dim3((unsigned)((WIH_ELEMS+255)/256)), dim3(256), 0, stream>>>(wih, wihp);
        k_gather_x<<<dim3((unsigned)((X_ELEMS+255)/256)),  dim3(256), 0, stream>>>(tokens, emb, xp);
        k_gi_gemm<<<dim3(24,150), dim3(256), 0, stream>>>(xp, wihp, (f16*)(ws + o_gi));

        hipFuncSetAttribute((const void*)k_rnn,
                            hipFuncAttributeMaxDynamicSharedMemorySize, 153600);
        void* args[] = { &A };
        hipError_t e = hipLaunchCooperativeKernel((const void*)k_rnn,
                            dim3(GRID_RNN), dim3(512), args, 153600, stream);
        ok = (e == hipSuccess);
    }

    if (!ok) {
        float* h32 = (float*)ws;
        float* hbuf[2] = { h32, h32 + HB };
        hipMemsetAsync(ws, 0, 2*HB*4, stream);
        for (int t=0; t<Tt; ++t){
            int c = t & 1, n = c ^ 1;
            k_fb_step<<<dim3(300), dim3(256), 0, stream>>>(t, hbuf[c], hbuf[n],
                tokens, lens, emb, wih, whh, bhh, out);
        }
    }
}

// Round 6
// 1876.165 us; speedup vs baseline: 14.6384x; 1.4789x over previous
//
#include <hip/hip_runtime.h>
#include <hip/hip_fp8.h>
#include <cstdint>
#include <cstddef>

typedef _Float16 f16;
typedef _Float16 f16x8 __attribute__((ext_vector_type(8)));
typedef float f32x4 __attribute__((ext_vector_type(4)));
typedef unsigned char u8;
typedef unsigned long long u64;

#define MFMA16(a,b,c) __builtin_amdgcn_mfma_f32_16x16x32_f16((a),(b),(c),0,0,0)
#define MFMA8(a,b,c)  __builtin_amdgcn_mfma_f32_16x16x32_fp8_fp8((long)(a),(long)(b),(c),0,0,0)

constexpr int Bb = 64, Tt = 48, Ee = 620, Hh = 2400;
constexpr int G3 = 3*Hh;        // 7200
constexpr int EPAD = 640;
constexpr int JT = Hh/16;       // 150
constexpr int KK_HH = Hh/32;    // 75
constexpr int KK_IH = EPAD/32;  // 20
constexpr int NT_ALL = G3/16;   // 450
constexpr int KKQ = 25;         // kk per K-third in k_step

constexpr size_t WHH_ELEMS = (size_t)NT_ALL*KK_HH*64*8;  // 17,280,000
constexpr size_t WIH_ELEMS = (size_t)NT_ALL*KK_IH*64*8;  // 4,608,000
constexpr size_t X_ELEMS   = (size_t)Bb*Tt*EPAD;
constexpr size_t GI_ELEMS  = (size_t)Bb*Tt*G3;
constexpr size_t HB        = (size_t)Bb*Hh;              // 153,600

constexpr float F16_MIN_NORMAL = 6.103515625e-05f;
constexpr float LO_SCALE = 8388608.0f;   // 2^23
constexpr float LO_INV   = 1.0f/8388608.0f;

__device__ __forceinline__ float sigf(float x){ return 1.0f/(1.0f+expf(-x)); }
__device__ __forceinline__ u8 to_fp8(float x){
    __hip_fp8_e4m3 v(x); return *(u8*)&v;
}

// ---- pack w_hh: hi f16 frags + lo fp8 (residual x 2^23) ----
// elem (nt,kk,l,j): W[nt*16+(l&15)][kk*32+((l>>4)<<3)+j]
__global__ __launch_bounds__(256) void k_pack_whh(const float* __restrict__ w,
                                                  f16* __restrict__ hi,
                                                  u8* __restrict__ lo8){
    size_t idx = (size_t)blockIdx.x*256 + threadIdx.x;
    if (idx >= WHH_ELEMS) return;
    int j = (int)(idx & 7);
    int l = (int)((idx >> 3) & 63);
    size_t rem = idx >> 9;
    int kk = (int)(rem % KK_HH);
    int nt = (int)(rem / KK_HH);
    int row = nt*16 + (l & 15);
    int k   = kk*32 + ((l >> 4) << 3) + j;
    float v = w[(size_t)row*Hh + k];
    f16 h = (fabsf(v) >= F16_MIN_NORMAL) ? (f16)v : (f16)0.0f;
    hi[idx]  = h;
    lo8[idx] = to_fp8((v - (float)h) * LO_SCALE);
}

__global__ __launch_bounds__(256) void k_pack_wih(const float* __restrict__ w, f16* __restrict__ p){
    size_t idx = (size_t)blockIdx.x*256 + threadIdx.x;
    if (idx >= WIH_ELEMS) return;
    int j = (int)(idx & 7);
    int l = (int)((idx >> 3) & 63);
    size_t rem = idx >> 9;
    int kk = (int)(rem % KK_IH);
    int nt = (int)(rem / KK_IH);
    int row = nt*16 + (l & 15);
    int k   = kk*32 + ((l >> 4) << 3) + j;
    float v = (k < Ee) ? w[(size_t)row*Ee + k] : 0.0f;
    p[idx] = (f16)v;
}

__global__ __launch_bounds__(256) void k_gather_x(const int* __restrict__ tokens,
                                                  const float* __restrict__ emb,
                                                  f16* __restrict__ x){
    size_t idx = (size_t)blockIdx.x*256 + threadIdx.x;
    if (idx >= X_ELEMS) return;
    int row = (int)(idx / EPAD);
    int e   = (int)(idx % EPAD);
    int tok = tokens[row];
    float v = (e < Ee) ? emb[(size_t)tok*Ee + e] : 0.0f;
    x[idx] = (f16)v;
}

// ---- gi = x @ w_ih^T  (R2-proven version, verbatim) ----
__global__ __launch_bounds__(256) void k_gi_gemm(const f16* __restrict__ x,
                                                 const f16* __restrict__ wp,
                                                 f16* __restrict__ gi){
    const int w = threadIdx.x >> 6;
    const int l = threadIdx.x & 63;
    const int m0  = blockIdx.x*64 + w*16;
    const int nt0 = blockIdx.y*3;

    f32x4 z4 = {0.f,0.f,0.f,0.f};
    f32x4 a0 = z4, a1 = z4, a2 = z4;

    const f16x8* pa  = (const f16x8*)(x + (size_t)(m0 + (l & 15))*EPAD + ((l >> 4) << 3));
    const f16x8* pb0 = (const f16x8*)(wp + ((size_t)((nt0+0)*KK_IH)*64 + l)*8);
    const f16x8* pb1 = (const f16x8*)(wp + ((size_t)((nt0+1)*KK_IH)*64 + l)*8);
    const f16x8* pb2 = (const f16x8*)(wp + ((size_t)((nt0+2)*KK_IH)*64 + l)*8);

    f16x8 ca = pa[0], cb0 = pb0[0], cb1 = pb1[0], cb2 = pb2[0];
    #pragma unroll
    for (int kk=0; kk<KK_IH; ++kk){
        f16x8 na, nb0, nb1, nb2;
        if (kk+1 < KK_IH){
            na  = pa [(size_t)(kk+1)*4];
            nb0 = pb0[(size_t)(kk+1)*64];
            nb1 = pb1[(size_t)(kk+1)*64];
            nb2 = pb2[(size_t)(kk+1)*64];
        }
        a0 = MFMA16(ca, cb0, a0);
        a1 = MFMA16(ca, cb1, a1);
        a2 = MFMA16(ca, cb2, a2);
        if (kk+1 < KK_IH){ ca = na; cb0 = nb0; cb1 = nb1; cb2 = nb2; }
    }
    const int rb = (l >> 4)*4;
    #pragma unroll
    for (int r=0; r<4; ++r){
        int m = m0 + rb + r;
        int b = m / Tt, t = m % Tt;
        size_t base = ((size_t)t*Bb + b)*G3;
        int n0 = nt0*16 + (l & 15);
        gi[base + n0     ] = (f16)a0[r];
        gi[base + n0 + 16] = (f16)a1[r];
        gi[base + n0 + 32] = (f16)a2[r];
    }
}

// ---- one GRU step, fused: 150 blocks x 768 thr (4 m-tiles x 3 K-thirds) ----
// inner loop: R2/R4-proven depth-1 peeled prefetch with named variables
__global__ __launch_bounds__(768) void k_step(
    int t,
    const f16* __restrict__ Hhi, const f16* __restrict__ Hlo,
    const u8* __restrict__ Hq8, const float* __restrict__ H32,
    f16* __restrict__ Nhi, f16* __restrict__ Nlo,
    u8* __restrict__ Nq8, float* __restrict__ N32,
    const f16* __restrict__ whi, const u8* __restrict__ wlo,
    const f16* __restrict__ gi, const float* __restrict__ bhh,
    const int* __restrict__ lens, float* __restrict__ out)
{
    __shared__ float red[2][4][64][13];
    const int tid = threadIdx.x;
    const int l  = tid & 63, wv = tid >> 6;
    const int m  = wv & 3, kq = wv >> 2;      // m-tile 0..3, K-third 0..2
    const int jt = blockIdx.x;                // 0..149

    const int row = m*16 + (l & 15);
    const int kl8 = (l >> 4) << 3;
    const int kb  = kq*KKQ;

    const size_t aoff = (size_t)row*Hh + (size_t)kb*32 + kl8;
    const f16* pah = Hhi + aoff;
    const f16* pal = Hlo + aoff;
    const u8*  paq = Hq8 + aoff;

    const f16* pbh0 = whi + ((size_t)((0*JT+jt)*KK_HH + kb)*64 + l)*8;
    const f16* pbh1 = whi + ((size_t)((1*JT+jt)*KK_HH + kb)*64 + l)*8;
    const f16* pbh2 = whi + ((size_t)((2*JT+jt)*KK_HH + kb)*64 + l)*8;
    const u8*  pbl0 = wlo + ((size_t)((0*JT+jt)*KK_HH + kb))*512 + (size_t)l*8;
    const u8*  pbl1 = wlo + ((size_t)((1*JT+jt)*KK_HH + kb))*512 + (size_t)l*8;
    const u8*  pbl2 = wlo + ((size_t)((2*JT+jt)*KK_HH + kb))*512 + (size_t)l*8;

    f32x4 z4 = {0.f,0.f,0.f,0.f};
    f32x4 ah0=z4, ah1=z4, ah2=z4;
    f32x4 al0=z4, al1=z4, al2=z4;

    f16x8 cah = *(const f16x8*)(pah);
    f16x8 cal = *(const f16x8*)(pal);
    u64   caq = *(const u64*)(paq);
    f16x8 cb0 = *(const f16x8*)(pbh0);
    f16x8 cb1 = *(const f16x8*)(pbh1);
    f16x8 cb2 = *(const f16x8*)(pbh2);
    u64   cl0 = *(const u64*)(pbl0);
    u64   cl1 = *(const u64*)(pbl1);
    u64   cl2 = *(const u64*)(pbl2);

    for (int it=0; it<KKQ-1; ++it){
        const int kn = it + 1;
        f16x8 nah = *(const f16x8*)(pah + (size_t)kn*32);
        f16x8 nal = *(const f16x8*)(pal + (size_t)kn*32);
        u64   naq = *(const u64*)(paq + (size_t)kn*32);
        f16x8 nb0 = *(const f16x8*)(pbh0 + (size_t)kn*512);
        f16x8 nb1 = *(const f16x8*)(pbh1 + (size_t)kn*512);
        f16x8 nb2 = *(const f16x8*)(pbh2 + (size_t)kn*512);
        u64   nl0 = *(const u64*)(pbl0 + (size_t)kn*512);
        u64   nl1 = *(const u64*)(pbl1 + (size_t)kn*512);
        u64   nl2 = *(const u64*)(pbl2 + (size_t)kn*512);

        ah0 = MFMA16(cah, cb0, ah0);
        al0 = MFMA16(cal, cb0, al0);
        al0 = MFMA8(caq, cl0, al0);
        ah1 = MFMA16(cah, cb1, ah1);
        al1 = MFMA16(cal, cb1, al1);
        al1 = MFMA8(caq, cl1, al1);
        ah2 = MFMA16(cah, cb2, ah2);
        al2 = MFMA16(cal, cb2, al2);
        al2 = MFMA8(caq, cl2, al2);

        cah=nah; cal=nal; caq=naq;
        cb0=nb0; cb1=nb1; cb2=nb2;
        cl0=nl0; cl1=nl1; cl2=nl2;
    }
    ah0 = MFMA16(cah, cb0, ah0);
    al0 = MFMA16(cal, cb0, al0);
    al0 = MFMA8(caq, cl0, al0);
    ah1 = MFMA16(cah, cb1, ah1);
    al1 = MFMA16(cal, cb1, al1);
    al1 = MFMA8(caq, cl1, al1);
    ah2 = MFMA16(cah, cb2, ah2);
    al2 = MFMA16(cal, cb2, al2);
    al2 = MFMA8(caq, cl2, al2);

    // ---- cross-K-third reduction via LDS ----
    if (kq > 0){
        f32x4 v0 = ah0 + al0*LO_INV;
        f32x4 v1 = ah1 + al1*LO_INV;
        f32x4 v2 = ah2 + al2*LO_INV;
        #pragma unroll
        for (int r=0; r<4; ++r){
            red[kq-1][m][l][r]   = v0[r];
            red[kq-1][m][l][4+r] = v1[r];
            red[kq-1][m][l][8+r] = v2[r];
        }
    }
    __syncthreads();
    if (kq == 0){
        const int j = jt*16 + (l & 15);
        const float br = bhh[j], bz = bhh[Hh + j], bn = bhh[2*Hh + j];
        f32x4 s0 = ah0 + al0*LO_INV;
        f32x4 s1 = ah1 + al1*LO_INV;
        f32x4 s2 = ah2 + al2*LO_INV;
        #pragma unroll
        for (int r=0; r<4; ++r){
            s0[r] += red[0][m][l][r]   + red[1][m][l][r];
            s1[r] += red[0][m][l][4+r] + red[1][m][l][4+r];
            s2[r] += red[0][m][l][8+r] + red[1][m][l][8+r];
        }
        const int rb = (l >> 4)*4;
        #pragma unroll
        for (int r=0; r<4; ++r){
            const int b = m*16 + rb + r;
            const f16* git = gi + ((size_t)t*Bb + b)*G3;
            float rg = sigf((float)git[j]         + s0[r] + br);
            float zg = sigf((float)git[Hh + j]    + s1[r] + bz);
            float ng = tanhf((float)git[2*Hh + j] + rg*(s2[r] + bn));
            const size_t hidx = (size_t)b*Hh + j;
            float hp = H32[hidx];
            float hn = (1.0f - zg)*ng + zg*hp;
            N32[hidx] = hn;
            f16 h16 = (fabsf(hn) >= F16_MIN_NORMAL) ? (f16)hn : (f16)0.0f;
            Nhi[hidx] = h16;
            Nlo[hidx] = (f16)((hn - (float)h16)*LO_SCALE);
            Nq8[hidx] = to_fp8(hn);
            if (lens[b] - 1 == t) out[hidx] = hn;
        }
    }
}

// ---- fallback (small ws): plain fp32 ----
__global__ __launch_bounds__(256) void k_fb_step(
    int t, const float* __restrict__ hcur, float* __restrict__ hnext,
    const int* __restrict__ tokens, const int* __restrict__ lens,
    const float* __restrict__ emb, const float* __restrict__ wih,
    const float* __restrict__ whh, const float* __restrict__ bhh,
    float* __restrict__ out)
{
    __shared__ float sbuf[64][17];
    __shared__ int stok[64];
    const int tid = threadIdx.x;
    const int jl = tid & 7, rl = tid >> 3;
    const int j = blockIdx.x*8 + jl;
    if (tid < 64) stok[tid] = tokens[tid*Tt + t];

    float accr[2]={0.f,0.f}, accz[2]={0.f,0.f}, accnh[2]={0.f,0.f}, accni[2]={0.f,0.f};

    for (int k0=0; k0<Hh; k0+=16){
        __syncthreads();
        for (int e=tid; e<1024; e+=256)
            sbuf[e>>4][e&15] = hcur[(size_t)(e>>4)*Hh + k0 + (e&15)];
        __syncthreads();
        for (int kk=0; kk<16; ++kk){
            int k = k0 + kk;
            float wr = whh[(size_t)j*Hh + k];
            float wz = whh[(size_t)(Hh + j)*Hh + k];
            float wn = whh[(size_t)(2*Hh + j)*Hh + k];
            #pragma unroll
            for (int rr=0; rr<2; ++rr){
                float hv = sbuf[rl*2 + rr][kk];
                accr[rr] += wr*hv; accz[rr] += wz*hv; accnh[rr] += wn*hv;
            }
        }
    }
    for (int k0=0; k0<Ee; k0+=16){
        int lim = (Ee - k0 < 16) ? (Ee - k0) : 16;
        __syncthreads();
        for (int e=tid; e<1024; e+=256){
            int rr = e>>4, kkk = e&15;
            sbuf[rr][kkk] = (kkk < lim) ? emb[(size_t)stok[rr]*Ee + k0 + kkk] : 0.0f;
        }
        __syncthreads();
        for (int kk=0; kk<lim; ++kk){
            int k = k0 + kk;
            float wr = wih[(size_t)j*Ee + k];
            float wz = wih[(size_t)(Hh + j)*Ee + k];
            float wn = wih[(size_t)(2*Hh + j)*Ee + k];
            #pragma unroll
            for (int rr=0; rr<2; ++rr){
                float hv = sbuf[rl*2 + rr][kk];
                accr[rr] += wr*hv; accz[rr] += wz*hv; accni[rr] += wn*hv;
            }
        }
    }
    const float br = bhh[j], bz = bhh[Hh + j], bn = bhh[2*Hh + j];
    #pragma unroll
    for (int rr=0; rr<2; ++rr){
        int b = rl*2 + rr;
        float rg = sigf(accr[rr] + br);
        float zg = sigf(accz[rr] + bz);
        float ng = tanhf(accni[rr] + rg*(accnh[rr] + bn));
        float hp = hcur[(size_t)b*Hh + j];
        float hn = (1.0f - zg)*ng + zg*hp;
        hnext[(size_t)b*Hh + j] = hn;
        if (lens[b] - 1 == t) out[(size_t)b*Hh + j] = hn;
    }
}

static inline size_t alignup(size_t v){ return (v + 255) & ~(size_t)255; }

extern "C" void kernel_launch(void* const* d_in, const int* in_sizes, int n_in,
                              void* d_out, int out_size, void* d_ws, size_t ws_size,
                              hipStream_t stream)
{
    const int*   tokens = (const int*)d_in[0];
    const int*   lens   = (const int*)d_in[1];
    const float* emb    = (const float*)d_in[2];
    const float* wih    = (const float*)d_in[3];
    const float* whh    = (const float*)d_in[4];
    const float* bhh    = (const float*)d_in[5];
    float* out = (float*)d_out;

    char* ws = (char*)d_ws;
    size_t o = 0;
    const size_t o_whi  = o; o = alignup(o + WHH_ELEMS*2);
    const size_t o_wlo8 = o; o = alignup(o + WHH_ELEMS);
    const size_t o_wih  = o; o = alignup(o + WIH_ELEMS*2);
    const size_t o_x    = o; o = alignup(o + X_ELEMS*2);
    const size_t o_gi   = o; o = alignup(o + GI_ELEMS*2);
    const size_t hbytes = HB*2 + HB*2 + HB + HB*4;   // hi, lo, q8, h32
    const size_t o_hbuf = o; o = alignup(o + 2*hbytes);
    const size_t need = o;   // ~112 MB

    if (ws_size >= need) {
        f16* whip = (f16*)(ws + o_whi);
        u8*  wlop = (u8*)(ws + o_wlo8);
        f16* wihp = (f16*)(ws + o_wih);
        f16* xp   = (f16*)(ws + o_x);
        f16* gip  = (f16*)(ws + o_gi);
        char* hb = ws + o_hbuf;
        f16* hhi[2]; f16* hlo[2]; u8* hq8[2]; float* h32[2];
        for (int i=0; i<2; ++i){
            char* p = hb + i*hbytes;
            hhi[i] = (f16*)p;
            hlo[i] = (f16*)(p + HB*2);
            hq8[i] = (u8*)(p + HB*4);
            h32[i] = (float*)(p + HB*5);
        }

        hipMemsetAsync(hb, 0, 2*hbytes, stream);
        k_pack_whh<<<dim3((unsigned)((WHH_ELEMS+255)/256)), dim3(256), 0, stream>>>(whh, whip, wlop);
        k_pack_wih<<<dim3((unsigned)((WIH_ELEMS+255)/256)), dim3(256), 0, stream>>>(wih, wihp);
        k_gather_x<<<dim3((unsigned)((X_ELEMS+255)/256)),  dim3(256), 0, stream>>>(tokens, emb, xp);
        k_gi_gemm<<<dim3(48,150), dim3(256), 0, stream>>>(xp, wihp, gip);
        for (int t=0; t<Tt; ++t){
            int c = t & 1, n = c ^ 1;
            k_step<<<dim3(JT), dim3(768), 0, stream>>>(t,
                hhi[c], hlo[c], hq8[c], h32[c],
                hhi[n], hlo[n], hq8[n], h32[n],
                whip, wlop, gip, bhh, lens, out);
        }
    } else {
        float* h32 = (float*)ws;
        float* hbuf[2] = { h32, h32 + HB };
        hipMemsetAsync(ws, 0, 2*HB*4, stream);
        for (int t=0; t<Tt; ++t){
            int c = t & 1, n = c ^ 1;
            k_fb_step<<<dim3(300), dim3(256), 0, stream>>>(t, hbuf[c], hbuf[n],
                tokens, lens, emb, wih, whh, bhh, out);
        }
    }
}

// Round 7
// 1577.290 us; speedup vs baseline: 17.4122x; 1.1895x over previous
//
#include <hip/hip_runtime.h>
#include <hip/hip_fp8.h>
#include <cstdint>
#include <cstddef>

typedef _Float16 f16;
typedef _Float16 f16x8 __attribute__((ext_vector_type(8)));
typedef float f32x4 __attribute__((ext_vector_type(4)));
typedef unsigned char u8;
typedef unsigned long long u64;

#define MFMA16(a,b,c) __builtin_amdgcn_mfma_f32_16x16x32_f16((a),(b),(c),0,0,0)
#define MFMA8(a,b,c)  __builtin_amdgcn_mfma_f32_16x16x32_fp8_fp8((long)(a),(long)(b),(c),0,0,0)

constexpr int Bb = 64, Tt = 48, Ee = 620, Hh = 2400;
constexpr int G3 = 3*Hh;        // 7200
constexpr int EPAD = 640;
constexpr int JT = Hh/16;       // 150
constexpr int KK_HH = Hh/32;    // 75
constexpr int KK_IH = EPAD/32;  // 20
constexpr int NT_ALL = G3/16;   // 450
constexpr int KS = 5;           // K-split for recurrence
constexpr int KKB = KK_HH/KS;   // 15

constexpr size_t WHH_ELEMS = (size_t)NT_ALL*KK_HH*64*8;  // 17,280,000
constexpr size_t WIH_ELEMS = (size_t)NT_ALL*KK_IH*64*8;  // 4,608,000
constexpr size_t X_ELEMS   = (size_t)Bb*Tt*EPAD;
constexpr size_t GI_ELEMS  = (size_t)Bb*Tt*G3;
constexpr size_t HB        = (size_t)Bb*Hh;              // 153,600

constexpr float F16_MIN_NORMAL = 6.103515625e-05f;
constexpr float LO_SCALE = 8388608.0f;   // 2^23
constexpr float LO_INV   = 1.0f/8388608.0f;

__device__ __forceinline__ float sigf(float x){ return 1.0f/(1.0f+expf(-x)); }
__device__ __forceinline__ u8 to_fp8(float x){
    __hip_fp8_e4m3 v(x); return *(u8*)&v;
}

// ---- pack w_hh: hi f16 frags + lo fp8 (residual x 2^23) ----
// elem (nt,kk,l,j): W[nt*16+(l&15)][kk*32+((l>>4)<<3)+j]
__global__ __launch_bounds__(256) void k_pack_whh(const float* __restrict__ w,
                                                  f16* __restrict__ hi,
                                                  u8* __restrict__ lo8){
    size_t idx = (size_t)blockIdx.x*256 + threadIdx.x;
    if (idx >= WHH_ELEMS) return;
    int j = (int)(idx & 7);
    int l = (int)((idx >> 3) & 63);
    size_t rem = idx >> 9;
    int kk = (int)(rem % KK_HH);
    int nt = (int)(rem / KK_HH);
    int row = nt*16 + (l & 15);
    int k   = kk*32 + ((l >> 4) << 3) + j;
    float v = w[(size_t)row*Hh + k];
    f16 h = (fabsf(v) >= F16_MIN_NORMAL) ? (f16)v : (f16)0.0f;
    hi[idx]  = h;
    lo8[idx] = to_fp8((v - (float)h) * LO_SCALE);
}

__global__ __launch_bounds__(256) void k_pack_wih(const float* __restrict__ w, f16* __restrict__ p){
    size_t idx = (size_t)blockIdx.x*256 + threadIdx.x;
    if (idx >= WIH_ELEMS) return;
    int j = (int)(idx & 7);
    int l = (int)((idx >> 3) & 63);
    size_t rem = idx >> 9;
    int kk = (int)(rem % KK_IH);
    int nt = (int)(rem / KK_IH);
    int row = nt*16 + (l & 15);
    int k   = kk*32 + ((l >> 4) << 3) + j;
    float v = (k < Ee) ? w[(size_t)row*Ee + k] : 0.0f;
    p[idx] = (f16)v;
}

__global__ __launch_bounds__(256) void k_gather_x(const int* __restrict__ tokens,
                                                  const float* __restrict__ emb,
                                                  f16* __restrict__ x){
    size_t idx = (size_t)blockIdx.x*256 + threadIdx.x;
    if (idx >= X_ELEMS) return;
    int row = (int)(idx / EPAD);
    int e   = (int)(idx % EPAD);
    int tok = tokens[row];
    float v = (e < Ee) ? emb[(size_t)tok*Ee + e] : 0.0f;
    x[idx] = (f16)v;
}

// ---- gi = x @ w_ih^T: R2 structure + LDS-staged B (shared by 4 waves) ----
__global__ __launch_bounds__(256) void k_gi_gemm(const f16* __restrict__ x,
                                                 const f16* __restrict__ wp,
                                                 f16* __restrict__ gi){
    __shared__ char smem[61440];   // 3 nt x 20 kk x 1KB
    const int tid = threadIdx.x;
    const int w = tid >> 6;
    const int l = tid & 63;
    const int m0  = blockIdx.x*64 + w*16;
    const int nt0 = blockIdx.y*3;

    // stage B hi: per g, 20480 B contiguous at (nt*20)*1024
    {
        const char* base = (const char*)wp;
        for (int off = tid*16; off < 61440; off += 4096){
            int g = off / 20480, rem = off - g*20480;
            const char* src = base + (size_t)(nt0+g)*20480 + rem;
            *(float4*)(smem + off) = *(const float4*)src;
        }
    }
    __syncthreads();

    f32x4 z4 = {0.f,0.f,0.f,0.f};
    f32x4 a0 = z4, a1 = z4, a2 = z4;

    const f16x8* pa = (const f16x8*)(x + (size_t)(m0 + (l & 15))*EPAD + ((l >> 4) << 3));
    const unsigned lbase = (unsigned)l*16u;

    f16x8 ca = pa[0];
    #pragma unroll
    for (int kk=0; kk<KK_IH; ++kk){
        f16x8 na;
        if (kk+1 < KK_IH) na = pa[(size_t)(kk+1)*4];
        f16x8 b0 = *(const f16x8*)(smem +      0u + (unsigned)kk*1024u + lbase);
        f16x8 b1 = *(const f16x8*)(smem + 20480u + (unsigned)kk*1024u + lbase);
        f16x8 b2 = *(const f16x8*)(smem + 40960u + (unsigned)kk*1024u + lbase);
        a0 = MFMA16(ca, b0, a0);
        a1 = MFMA16(ca, b1, a1);
        a2 = MFMA16(ca, b2, a2);
        if (kk+1 < KK_IH) ca = na;
    }
    const int rb = (l >> 4)*4;
    #pragma unroll
    for (int r=0; r<4; ++r){
        int m = m0 + rb + r;
        int b = m / Tt, t = m % Tt;
        size_t base = ((size_t)t*Bb + b)*G3;
        int n0 = nt0*16 + (l & 15);
        gi[base + n0     ] = (f16)a0[r];
        gi[base + n0 + 16] = (f16)a1[r];
        gi[base + n0 + 32] = (f16)a2[r];
    }
}

// ---- recurrence GEMM, K-split, LDS-staged B (hi f16 + lo fp8) ----
__global__ __launch_bounds__(256) void k_gru_mfma(
    const f16* __restrict__ hhi, const f16* __restrict__ hlo, const u8* __restrict__ hq8,
    const f16* __restrict__ whi, const u8* __restrict__ wlo,
    float* __restrict__ part)
{
    __shared__ char smem[69120];   // hi: 3x15x1024=46080 | lo8: 3x15x512=23040
    const int tid = threadIdx.x;
    const int w  = tid >> 6;       // wave = M-tile (16 batch rows)
    const int l  = tid & 63;
    const int jt = blockIdx.x;     // 0..149
    const int ks = blockIdx.y;     // 0..4

    // ---- stage this block's B slice into LDS (once, shared by 4 waves) ----
    {
        const char* bh = (const char*)whi;
        for (int off = tid*16; off < 46080; off += 4096){
            int g = off / 15360, rem = off - g*15360;
            size_t nt = (size_t)(g*JT + jt);
            const char* src = bh + (nt*KK_HH + ks*KKB)*1024 + rem;
            *(float4*)(smem + off) = *(const float4*)src;
        }
        const char* bl = (const char*)wlo;
        for (int off = tid*16; off < 23040; off += 4096){
            int g = off / 7680, rem = off - g*7680;
            size_t nt = (size_t)(g*JT + jt);
            const char* src = bl + (nt*KK_HH + ks*KKB)*512 + rem;
            *(float4*)(smem + 46080 + off) = *(const float4*)src;
        }
    }
    __syncthreads();

    const size_t aoff = (size_t)(w*16 + (l & 15))*Hh + ks*(KKB*32) + ((l >> 4) << 3);
    const f16* pah = hhi + aoff;
    const f16* pal = hlo + aoff;
    const u8*  paq = hq8 + aoff;
    const unsigned lb128 = (unsigned)l*16u;
    const unsigned lb64  = (unsigned)l*8u;

    f32x4 z4 = {0.f,0.f,0.f,0.f};
    f32x4 ah0=z4, ah1=z4, ah2=z4;
    f32x4 al0=z4, al1=z4, al2=z4;

    f16x8 cah = *(const f16x8*)(pah);
    f16x8 cal = *(const f16x8*)(pal);
    u64   caq = *(const u64*)(paq);

    for (int kk=0; kk<KKB; ++kk){
        f16x8 nah, nal; u64 naq;
        if (kk+1 < KKB){
            nah = *(const f16x8*)(pah + (size_t)(kk+1)*32);
            nal = *(const f16x8*)(pal + (size_t)(kk+1)*32);
            naq = *(const u64*)(paq + (size_t)(kk+1)*32);
        }
        const unsigned kh = (unsigned)kk*1024u + lb128;
        const unsigned kl = (unsigned)kk*512u  + lb64;
        f16x8 b0 = *(const f16x8*)(smem +      0u + kh);
        f16x8 b1 = *(const f16x8*)(smem + 15360u + kh);
        f16x8 b2 = *(const f16x8*)(smem + 30720u + kh);
        u64 l0 = *(const u64*)(smem + 46080u +     0u + kl);
        u64 l1 = *(const u64*)(smem + 46080u +  7680u + kl);
        u64 l2 = *(const u64*)(smem + 46080u + 15360u + kl);

        ah0 = MFMA16(cah, b0, ah0);
        al0 = MFMA16(cal, b0, al0);
        al0 = MFMA8(caq, l0, al0);
        ah1 = MFMA16(cah, b1, ah1);
        al1 = MFMA16(cal, b1, al1);
        al1 = MFMA8(caq, l1, al1);
        ah2 = MFMA16(cah, b2, ah2);
        al2 = MFMA16(cal, b2, al2);
        al2 = MFMA8(caq, l2, al2);

        if (kk+1 < KKB){ cah=nah; cal=nal; caq=naq; }
    }

    const int j = jt*16 + (l & 15);
    const int rbase = (l >> 4)*4;
    #pragma unroll
    for (int r=0; r<4; ++r){
        const int b = w*16 + rbase + r;
        part[((size_t)(0*KS+ks)*Bb + b)*Hh + j] = ah0[r] + al0[r]*LO_INV;
        part[((size_t)(1*KS+ks)*Bb + b)*Hh + j] = ah1[r] + al1[r]*LO_INV;
        part[((size_t)(2*KS+ks)*Bb + b)*Hh + j] = ah2[r] + al2[r]*LO_INV;
    }
}

// ---- sum K-split partials + gates + h update + length-select output ----
__global__ __launch_bounds__(256) void k_combine(
    int t, const float* __restrict__ part, const f16* __restrict__ gi,
    const float* __restrict__ h32, float* __restrict__ nh32,
    f16* __restrict__ nhhi, f16* __restrict__ nhlo, u8* __restrict__ nhq8,
    const float* __restrict__ bhh, const int* __restrict__ lens,
    float* __restrict__ out)
{
    const int idx = blockIdx.x*256 + threadIdx.x;   // 0 .. 153599
    const int b = idx / Hh, j = idx - b*Hh;
    float sr = 0.f, sz = 0.f, sn = 0.f;
    #pragma unroll
    for (int ks=0; ks<KS; ++ks){
        sr += part[((size_t)(0*KS+ks)*Bb + b)*Hh + j];
        sz += part[((size_t)(1*KS+ks)*Bb + b)*Hh + j];
        sn += part[((size_t)(2*KS+ks)*Bb + b)*Hh + j];
    }
    const f16* git = gi + ((size_t)t*Bb + b)*G3;
    float rg = sigf((float)git[j]        + sr + bhh[j]);
    float zg = sigf((float)git[Hh + j]   + sz + bhh[Hh + j]);
    float ng = tanhf((float)git[2*Hh + j] + rg*(sn + bhh[2*Hh + j]));
    float hp = h32[idx];
    float hn = (1.0f - zg)*ng + zg*hp;
    nh32[idx] = hn;
    f16 h16 = (fabsf(hn) >= F16_MIN_NORMAL) ? (f16)hn : (f16)0.0f;
    nhhi[idx] = h16;
    nhlo[idx] = (f16)((hn - (float)h16)*LO_SCALE);
    nhq8[idx] = to_fp8(hn);
    if (lens[b] - 1 == t) out[idx] = hn;
}

// ---- fallback (small ws): plain fp32 ----
__global__ __launch_bounds__(256) void k_fb_step(
    int t, const float* __restrict__ hcur, float* __restrict__ hnext,
    const int* __restrict__ tokens, const int* __restrict__ lens,
    const float* __restrict__ emb, const float* __restrict__ wih,
    const float* __restrict__ whh, const float* __restrict__ bhh,
    float* __restrict__ out)
{
    __shared__ float sbuf[64][17];
    __shared__ int stok[64];
    const int tid = threadIdx.x;
    const int jl = tid & 7, rl = tid >> 3;
    const int j = blockIdx.x*8 + jl;
    if (tid < 64) stok[tid] = tokens[tid*Tt + t];

    float accr[2]={0.f,0.f}, accz[2]={0.f,0.f}, accnh[2]={0.f,0.f}, accni[2]={0.f,0.f};

    for (int k0=0; k0<Hh; k0+=16){
        __syncthreads();
        for (int e=tid; e<1024; e+=256)
            sbuf[e>>4][e&15] = hcur[(size_t)(e>>4)*Hh + k0 + (e&15)];
        __syncthreads();
        for (int kk=0; kk<16; ++kk){
            int k = k0 + kk;
            float wr = whh[(size_t)j*Hh + k];
            float wz = whh[(size_t)(Hh + j)*Hh + k];
            float wn = whh[(size_t)(2*Hh + j)*Hh + k];
            #pragma unroll
            for (int rr=0; rr<2; ++rr){
                float hv = sbuf[rl*2 + rr][kk];
                accr[rr] += wr*hv; accz[rr] += wz*hv; accnh[rr] += wn*hv;
            }
        }
    }
    for (int k0=0; k0<Ee; k0+=16){
        int lim = (Ee - k0 < 16) ? (Ee - k0) : 16;
        __syncthreads();
        for (int e=tid; e<1024; e+=256){
            int rr = e>>4, kkk = e&15;
            sbuf[rr][kkk] = (kkk < lim) ? emb[(size_t)stok[rr]*Ee + k0 + kkk] : 0.0f;
        }
        __syncthreads();
        for (int kk=0; kk<lim; ++kk){
            int k = k0 + kk;
            float wr = wih[(size_t)j*Ee + k];
            float wz = wih[(size_t)(Hh + j)*Ee + k];
            float wn = wih[(size_t)(2*Hh + j)*Ee + k];
            #pragma unroll
            for (int rr=0; rr<2; ++rr){
                float hv = sbuf[rl*2 + rr][kk];
                accr[rr] += wr*hv; accz[rr] += wz*hv; accni[rr] += wn*hv;
            }
        }
    }
    const float br = bhh[j], bz = bhh[Hh + j], bn = bhh[2*Hh + j];
    #pragma unroll
    for (int rr=0; rr<2; ++rr){
        int b = rl*2 + rr;
        float rg = sigf(accr[rr] + br);
        float zg = sigf(accz[rr] + bz);
        float ng = tanhf(accni[rr] + rg*(accnh[rr] + bn));
        float hp = hcur[(size_t)b*Hh + j];
        float hn = (1.0f - zg)*ng + zg*hp;
        hnext[(size_t)b*Hh + j] = hn;
        if (lens[b] - 1 == t) out[(size_t)b*Hh + j] = hn;
    }
}

static inline size_t alignup(size_t v){ return (v + 255) & ~(size_t)255; }

extern "C" void kernel_launch(void* const* d_in, const int* in_sizes, int n_in,
                              void* d_out, int out_size, void* d_ws, size_t ws_size,
                              hipStream_t stream)
{
    const int*   tokens = (const int*)d_in[0];
    const int*   lens   = (const int*)d_in[1];
    const float* emb    = (const float*)d_in[2];
    const float* wih    = (const float*)d_in[3];
    const float* whh    = (const float*)d_in[4];
    const float* bhh    = (const float*)d_in[5];
    float* out = (float*)d_out;

    char* ws = (char*)d_ws;
    size_t o = 0;
    const size_t o_whi  = o; o = alignup(o + WHH_ELEMS*2);
    const size_t o_wlo8 = o; o = alignup(o + WHH_ELEMS);
    const size_t o_wih  = o; o = alignup(o + WIH_ELEMS*2);  // reused as `part` after gi
    const size_t o_x    = o; o = alignup(o + X_ELEMS*2);
    const size_t o_gi   = o; o = alignup(o + GI_ELEMS*2);
    const size_t hbytes = HB*2 + HB*2 + HB + HB*4;   // hi, lo, q8, h32
    const size_t o_hbuf = o; o = alignup(o + 2*hbytes);
    const size_t need = o;   // ~112 MB

    if (ws_size >= need) {
        f16* whip = (f16*)(ws + o_whi);
        u8*  wlop = (u8*)(ws + o_wlo8);
        f16* wihp = (f16*)(ws + o_wih);
        float* part = (float*)(ws + o_wih);   // overlays wihp (dead after gi GEMM)
        f16* xp   = (f16*)(ws + o_x);
        f16* gip  = (f16*)(ws + o_gi);
        char* hb = ws + o_hbuf;
        f16* hhi[2]; f16* hlo[2]; u8* hq8[2]; float* h32[2];
        for (int i=0; i<2; ++i){
            char* p = hb + i*hbytes;
            hhi[i] = (f16*)p;
            hlo[i] = (f16*)(p + HB*2);
            hq8[i] = (u8*)(p + HB*4);
            h32[i] = (float*)(p + HB*5);
        }

        hipMemsetAsync(hb, 0, 2*hbytes, stream);
        k_pack_whh<<<dim3((unsigned)((WHH_ELEMS+255)/256)), dim3(256), 0, stream>>>(whh, whip, wlop);
        k_pack_wih<<<dim3((unsigned)((WIH_ELEMS+255)/256)), dim3(256), 0, stream>>>(wih, wihp);
        k_gather_x<<<dim3((unsigned)((X_ELEMS+255)/256)),  dim3(256), 0, stream>>>(tokens, emb, xp);
        k_gi_gemm<<<dim3(48,150), dim3(256), 0, stream>>>(xp, wihp, gip);
        for (int t=0; t<Tt; ++t){
            int c = t & 1, n = c ^ 1;
            k_gru_mfma<<<dim3(JT, KS), dim3(256), 0, stream>>>(
                hhi[c], hlo[c], hq8[c], whip, wlop, part);
            k_combine<<<dim3(600), dim3(256), 0, stream>>>(t, part, gip,
                h32[c], h32[n], hhi[n], hlo[n], hq8[n], bhh, lens, out);
        }
    } else {
        float* h32 = (float*)ws;
        float* hbuf[2] = { h32, h32 + HB };
        hipMemsetAsync(ws, 0, 2*HB*4, stream);
        for (int t=0; t<Tt; ++t){
            int c = t & 1, n = c ^ 1;
            k_fb_step<<<dim3(300), dim3(256), 0, stream>>>(t, hbuf[c], hbuf[n],
                tokens, lens, emb, wih, whh, bhh, out);
        }
    }
}